// Round 3
// baseline (532.939 us; speedup 1.0000x reference)
//
#include <hip/hip_runtime.h>

#define OD 26
#define OH 122
#define OW 122
#define GS (128*128)
#define NOUT (OD*OH*OW)

// Stage 0: domain kernel dk[27] — voxel-independent, computed once.
__global__ void compute_dk_kernel(const float* __restrict__ dn,
                                  const float* __restrict__ dw0, const float* __restrict__ db0,
                                  const float* __restrict__ dw1, const float* __restrict__ db1,
                                  float* __restrict__ dk_out) {
    __shared__ float d0[125];
    int t = threadIdx.x;
    if (t < 125) {
        int tz = t / 25, ty = (t / 5) % 5, tx = t % 5;
        float acc = db0[0];
        #pragma unroll
        for (int kz = 0; kz < 3; ++kz)
            #pragma unroll
            for (int ky = 0; ky < 3; ++ky)
                #pragma unroll
                for (int kx = 0; kx < 3; ++kx)
                    acc += dw0[kz*9 + ky*3 + kx] *
                           dn[(1+tz+kz)*81 + (1+ty+ky)*9 + (1+tx+kx)];
        d0[t] = fmaxf(acc, 0.0f);
    }
    __syncthreads();
    if (t < 27) {
        int rz = t / 9, ry = (t / 3) % 3, rx = t % 3;
        float acc = db1[0];
        #pragma unroll
        for (int kz = 0; kz < 3; ++kz)
            #pragma unroll
            for (int ky = 0; ky < 3; ++ky)
                #pragma unroll
                for (int kx = 0; kx < 3; ++kx)
                    acc += dw1[kz*9 + ky*3 + kx] * d0[(rz+kz)*25 + (ry+ky)*5 + (rx+kx)];
        dk_out[t] = fmaxf(acc, 0.0f);
    }
}

// One thread per output voxel. Rolling 3-slice conv1 window (live set ~130
// floats) + fused conv2 + explicit one-row-ahead guide prefetch.
// NOTE: plain __launch_bounds__(256). Do NOT add a min-waves arg: R2 showed
// (64,4) makes the allocator clamp to 64 VGPRs and spill ~590 B/thread
// (WRITE_SIZE 1.5MB -> 890MB, 148us -> 430us).
__global__ __launch_bounds__(256) void jbf_main_kernel(
        const float* __restrict__ x, const float* __restrict__ guide,
        const float* __restrict__ rw0p, const float* __restrict__ rb0p,
        const float* __restrict__ rw1p, const float* __restrict__ rb1p,
        const float* __restrict__ dkp, float* __restrict__ out) {
    int idx = blockIdx.x * 256 + threadIdx.x;
    if (idx >= NOUT) return;
    int x0 = idx % OW;
    int y0 = (idx / OW) % OH;
    int z0 = idx / (OW * OH);

    // Wave-uniform weights -> scalar regs (SGPR_Count 96/112 in R1/R2 confirms).
    float rw0[27], rw1[27];
    #pragma unroll
    for (int i = 0; i < 27; ++i) { rw0[i] = rw0p[i]; rw1[i] = rw1p[i]; }
    const float rb0 = rb0p[0], rb1 = rb1p[0];

    const float* gbase = guide + z0*GS + y0*128 + x0;
    const float gc = gbase[3*GS + 3*128 + 3];

    float t0[3][25];    // rolling z-window of conv1 slices (slot = tz % 3)
    float acc[27];      // conv2 accumulators
    float xv[27];       // epilogue x-patch, prefetched during last slice
    #pragma unroll
    for (int i = 0; i < 27; ++i) acc[i] = rb1;

    // Double-buffered guide row: row r+1 loads issue during row r's FMAs.
    float g0[7], g1[7];
    #pragma unroll
    for (int j = 0; j < 7; ++j) g0[j] = gbase[j];

    #pragma unroll
    for (int r = 0; r < 49; ++r) {          // row r = (gz, gy), fully unrolled
        const int gz = r / 7, gy = r % 7;
        float* curp = (r & 1) ? g1 : g0;
        float* nxtp = (r & 1) ? g0 : g1;

        // Prefetch next guide row (hidden under this row's 135 FMAs).
        if (r < 48) {
            const int nz = (r + 1) / 7, ny = (r + 1) % 7;
            const float* np = gbase + nz*GS + ny*128;
            #pragma unroll
            for (int j = 0; j < 7; ++j) nxtp[j] = np[j];
        }
        // Prefetch epilogue x-patch at start of the final z-slice (register
        // pressure has dropped by then: only slice tz=4 still live).
        if (r == 42) {
            const float* xb = x + (z0+2)*GS + (y0+2)*128 + (x0+2);
            #pragma unroll
            for (int rz = 0; rz < 3; ++rz)
                #pragma unroll
                for (int ry = 0; ry < 3; ++ry)
                    #pragma unroll
                    for (int rx = 0; rx < 3; ++rx)
                        xv[rz*9 + ry*3 + rx] = xb[rz*GS + ry*128 + rx];
        }

        // New conv1 slice tz==gz enters the window at gy==0 (tz<=4 only).
        if (gy == 0 && gz <= 4) {
            const int sl = gz % 3;
            #pragma unroll
            for (int i = 0; i < 25; ++i) t0[sl][i] = rb0;
        }

        // s = g - gc; fabs folds into the FMA as an abs() src modifier.
        float s[7];
        #pragma unroll
        for (int j = 0; j < 7; ++j) s[j] = curp[j] - gc;

        #pragma unroll
        for (int kz = 0; kz < 3; ++kz) {
            const int tz = gz - kz;
            if (tz < 0 || tz > 4) continue;          // folds at compile time
            const int tsl = tz % 3;
            #pragma unroll
            for (int ky = 0; ky < 3; ++ky) {
                const int ty = gy - ky;
                if (ty < 0 || ty > 4) continue;      // folds at compile time
                #pragma unroll
                for (int tx = 0; tx < 5; ++tx)
                    #pragma unroll
                    for (int kx = 0; kx < 3; ++kx)
                        t0[tsl][ty*5 + tx] =
                            fmaf(rw0[kz*9 + ky*3 + kx], fabsf(s[tx + kx]),
                                 t0[tsl][ty*5 + tx]);
            }
        }

        // After the last row of gz, slice tzc = gz-2 is complete:
        // ReLU + fold into conv2 accumulators, then recycle its registers.
        if (gy == 6) {
            const int tzc = gz - 2;
            if (tzc >= 0 && tzc <= 4) {
                const int csl = tzc % 3;
                #pragma unroll
                for (int i = 0; i < 25; ++i) t0[csl][i] = fmaxf(t0[csl][i], 0.0f);
                #pragma unroll
                for (int rz = 0; rz < 3; ++rz) {
                    const int kz2 = tzc - rz;
                    if (kz2 < 0 || kz2 > 2) continue;    // folds at compile time
                    #pragma unroll
                    for (int ry = 0; ry < 3; ++ry)
                        #pragma unroll
                        for (int rx = 0; rx < 3; ++rx)
                            #pragma unroll
                            for (int ky = 0; ky < 3; ++ky)
                                #pragma unroll
                                for (int kx = 0; kx < 3; ++kx)
                                    acc[rz*9 + ry*3 + rx] =
                                        fmaf(rw1[kz2*9 + ky*3 + kx],
                                             t0[csl][(ry+ky)*5 + (rx+kx)],
                                             acc[rz*9 + ry*3 + rx]);
                }
            }
        }
    }

    // Epilogue: domain*range weights, weighted average of the 3^3 x-patch.
    float num = 0.0f, den = 0.0f;
    #pragma unroll
    for (int i = 0; i < 27; ++i) {
        const float w = dkp[i] * fmaxf(acc[i], 0.0f) + 1e-10f;
        den += w;
        num = fmaf(w, xv[i], num);
    }
    out[idx] = num / den;
}

extern "C" void kernel_launch(void* const* d_in, const int* in_sizes, int n_in,
                              void* d_out, int out_size, void* d_ws, size_t ws_size,
                              hipStream_t stream) {
    const float* x     = (const float*)d_in[0];
    const float* dn    = (const float*)d_in[1];
    const float* guide = (const float*)d_in[2];
    const float* rw0   = (const float*)d_in[3];
    const float* rb0   = (const float*)d_in[4];
    const float* rw1   = (const float*)d_in[5];
    const float* rb1   = (const float*)d_in[6];
    const float* dw0   = (const float*)d_in[7];
    const float* db0   = (const float*)d_in[8];
    const float* dw1   = (const float*)d_in[9];
    const float* db1   = (const float*)d_in[10];
    float* out = (float*)d_out;
    float* dk  = (float*)d_ws;   // 27 floats

    compute_dk_kernel<<<1, 128, 0, stream>>>(dn, dw0, db0, dw1, db1, dk);

    int nblk = (NOUT + 255) / 256;
    jbf_main_kernel<<<nblk, 256, 0, stream>>>(x, guide, rw0, rb0, rw1, rb1, dk, out);
}

// Round 4
// 147.488 us; speedup vs baseline: 3.6134x; 3.6134x over previous
//
#include <hip/hip_runtime.h>

#define OD 26
#define OH 122
#define OW 122
#define GS (128*128)
#define NOUT (OD*OH*OW)

// Guide LDS tile: (8+6) x (8+6) x (4+6) for an 8x8x4 voxel block.
#define TLX 14
#define TLY 14
#define TLZ 10
#define TLSLICE (TLX*TLY)      // 196
#define TLN (TLSLICE*TLZ)      // 1960 floats = 7.84 KB

// Stage 0: domain kernel dk[27] — voxel-independent, computed once.
__global__ void compute_dk_kernel(const float* __restrict__ dn,
                                  const float* __restrict__ dw0, const float* __restrict__ db0,
                                  const float* __restrict__ dw1, const float* __restrict__ db1,
                                  float* __restrict__ dk_out) {
    __shared__ float d0[125];
    int t = threadIdx.x;
    if (t < 125) {
        int tz = t / 25, ty = (t / 5) % 5, tx = t % 5;
        float acc = db0[0];
        #pragma unroll
        for (int kz = 0; kz < 3; ++kz)
            #pragma unroll
            for (int ky = 0; ky < 3; ++ky)
                #pragma unroll
                for (int kx = 0; kx < 3; ++kx)
                    acc += dw0[kz*9 + ky*3 + kx] *
                           dn[(1+tz+kz)*81 + (1+ty+ky)*9 + (1+tx+kx)];
        d0[t] = fmaxf(acc, 0.0f);
    }
    __syncthreads();
    if (t < 27) {
        int rz = t / 9, ry = (t / 3) % 3, rx = t % 3;
        float acc = db1[0];
        #pragma unroll
        for (int kz = 0; kz < 3; ++kz)
            #pragma unroll
            for (int ky = 0; ky < 3; ++ky)
                #pragma unroll
                for (int kx = 0; kx < 3; ++kx)
                    acc += dw1[kz*9 + ky*3 + kx] * d0[(rz+kz)*25 + (ry+ky)*5 + (rx+kx)];
        dk_out[t] = fmaxf(acc, 0.0f);
    }
}

// Block = 8x8x4 voxel tile (256 threads). Guide tile staged in LDS; then
// R1's proven spill-free full-t0[125] per-thread compute, reading guide from
// LDS with immediate ds_read offsets.
//
// DO NOT add a min-waves arg or restructure into a rolling register window:
// R2 ((64,4) hint) and R3 (rolling window, plain bounds) both made the
// allocator target high occupancy and spill ~600-800 B/thread to scratch
// (WRITE_SIZE 0.9-1.25 GB, 3x slower). Full t0[125] + plain bounds is the
// only structure the allocator has handled spill-free (R1: 164 VGPR).
__global__ __launch_bounds__(256) void jbf_main_kernel(
        const float* __restrict__ x, const float* __restrict__ guide,
        const float* __restrict__ rw0p, const float* __restrict__ rb0p,
        const float* __restrict__ rw1p, const float* __restrict__ rb1p,
        const float* __restrict__ dkp, float* __restrict__ out) {
    __shared__ float gl[TLN];

    const int xb = blockIdx.x * 8;
    const int yb = blockIdx.y * 8;
    const int zb = blockIdx.z * 4;

    // Cooperative guide staging, coords clamped (edge tiles read dup rows;
    // in-range voxels only consume in-bounds neighbors, so values are exact).
    for (int i = threadIdx.x; i < TLN; i += 256) {
        const int gx = i % TLX;
        const int gy = (i / TLX) % TLY;
        const int gz = i / TLSLICE;
        const int sx = min(xb + gx, 127);
        const int sy = min(yb + gy, 127);
        const int sz = min(zb + gz, 31);
        gl[i] = guide[sz*GS + sy*128 + sx];
    }
    __syncthreads();

    const int tx = threadIdx.x & 7;
    const int ty = (threadIdx.x >> 3) & 7;
    const int tz = threadIdx.x >> 6;
    const int x0 = xb + tx;
    const int y0 = yb + ty;
    const int z0 = zb + tz;
    if (x0 >= OW || y0 >= OH || z0 >= OD) return;

    // Wave-uniform weights -> scalar regs.
    float rw0[27], rw1[27];
    #pragma unroll
    for (int i = 0; i < 27; ++i) { rw0[i] = rw0p[i]; rw1[i] = rw1p[i]; }
    const float rb0 = rb0p[0], rb1 = rb1p[0];

    // Per-thread LDS base: all inner reads are base + compile-time offset.
    const float* glb = &gl[tz*TLSLICE + ty*TLX + tx];
    const float gc = glb[3*TLSLICE + 3*TLX + 3];

    // conv1: full 5x5x5 t0, accumulated row-by-row over the 49 guide rows.
    float t0[125];
    #pragma unroll
    for (int i = 0; i < 125; ++i) t0[i] = rb0;

    #pragma unroll
    for (int gz = 0; gz < 7; ++gz) {
        #pragma unroll
        for (int gy = 0; gy < 7; ++gy) {
            float s[7];
            #pragma unroll
            for (int j = 0; j < 7; ++j)
                s[j] = glb[gz*TLSLICE + gy*TLX + j] - gc;   // ds_read imm offset
            #pragma unroll
            for (int kz = 0; kz < 3; ++kz) {
                const int tz1 = gz - kz;
                if (tz1 < 0 || tz1 > 4) continue;        // folds at compile time
                #pragma unroll
                for (int ky = 0; ky < 3; ++ky) {
                    const int ty1 = gy - ky;
                    if (ty1 < 0 || ty1 > 4) continue;    // folds at compile time
                    #pragma unroll
                    for (int txx = 0; txx < 5; ++txx)
                        #pragma unroll
                        for (int kx = 0; kx < 3; ++kx)
                            t0[tz1*25 + ty1*5 + txx] =
                                fmaf(rw0[kz*9 + ky*3 + kx], fabsf(s[txx + kx]),
                                     t0[tz1*25 + ty1*5 + txx]);
                }
            }
        }
    }
    #pragma unroll
    for (int i = 0; i < 125; ++i) t0[i] = fmaxf(t0[i], 0.0f);

    // conv2 fused with weighting + reduction (rk never materialized).
    float num = 0.0f, den = 0.0f;
    const float* xbp = x + (z0+2)*GS + (y0+2)*128 + (x0+2);
    #pragma unroll
    for (int rz = 0; rz < 3; ++rz)
        #pragma unroll
        for (int ry = 0; ry < 3; ++ry)
            #pragma unroll
            for (int rx = 0; rx < 3; ++rx) {
                float acc = rb1;
                #pragma unroll
                for (int kz = 0; kz < 3; ++kz)
                    #pragma unroll
                    for (int ky = 0; ky < 3; ++ky)
                        #pragma unroll
                        for (int kx = 0; kx < 3; ++kx)
                            acc = fmaf(rw1[kz*9 + ky*3 + kx],
                                       t0[(rz+kz)*25 + (ry+ky)*5 + (rx+kx)], acc);
                const float w = dkp[rz*9 + ry*3 + rx] * fmaxf(acc, 0.0f) + 1e-10f;
                den += w;
                num = fmaf(w, xbp[rz*GS + ry*128 + rx], num);
            }

    out[(z0*OH + y0)*OW + x0] = num / den;
}

extern "C" void kernel_launch(void* const* d_in, const int* in_sizes, int n_in,
                              void* d_out, int out_size, void* d_ws, size_t ws_size,
                              hipStream_t stream) {
    const float* x     = (const float*)d_in[0];
    const float* dn    = (const float*)d_in[1];
    const float* guide = (const float*)d_in[2];
    const float* rw0   = (const float*)d_in[3];
    const float* rb0   = (const float*)d_in[4];
    const float* rw1   = (const float*)d_in[5];
    const float* rb1   = (const float*)d_in[6];
    const float* dw0   = (const float*)d_in[7];
    const float* db0   = (const float*)d_in[8];
    const float* dw1   = (const float*)d_in[9];
    const float* db1   = (const float*)d_in[10];
    float* out = (float*)d_out;
    float* dk  = (float*)d_ws;   // 27 floats

    compute_dk_kernel<<<1, 128, 0, stream>>>(dn, dw0, db0, dw1, db1, dk);

    dim3 grid((OW + 7) / 8, (OH + 7) / 8, (OD + 3) / 4);   // 16 x 16 x 7
    jbf_main_kernel<<<grid, 256, 0, stream>>>(x, guide, rw0, rb0, rw1, rb1, dk, out);
}